// Round 13
// baseline (928.042 us; speedup 1.0000x reference)
//
#include <hip/hip_runtime.h>

// Batched Jacobi diffusion, B=8, 128x128, iters=1000. One 1024-thread block
// per batch. Wave-strip layout: 16 waves x 8 grid rows; lane owns a float2
// column pair. VALU-PIPE-bound on 8 active CUs (~83% busy there).
//
// Round 26: move the horizontal shifts off the VALU pipe.
// Register war concluded (r14/r15/r18/r24/r25): allocator pins 64 arch VGPR
// + 64 AGPR-parked coefs; ~64 v_accvgpr_read/wave/step churn is immovable
// (5 attribute/constraint attempts, 0 moved VGPR_Count). Multi-block and
// multi-launch sync transports all measured dead (r16/r19/r20/r22), and
// r19's numbers show even zero-cost sync only reaches ~450-490us (fixed
// per-step costs don't shrink). So: shave the VALU pipe directly.
//   Old horizontal path: 2 old-movs + 2 DPP movs = 4 VALU instr/row.
//   New: 2 ds_bpermute_b32 (LDS pipe -- crossbar, lgkmcnt, no VALU slot,
//   no bank conflicts) + 2 v_cndmask boundary fixes (masks hoisted to SGPR
//   pairs since l==0/l==63 are lane-invariant) = 2 VALU instr/row.
//   LDS pipe budget: 256 bperm/CU/step x 2clk = 512cy < step time; pipe was
//   near-idle. Values bit-identical to the DPP path (same clamps).
// -16 VALU instr/wave/step: 134 -> ~118 => dur ~470-510us expected.
// FORCE_V8 retained from r25 (marginal positive, zero instructions).

#define GH 128
#define GW 128
#define NW 16      // waves per block
#define RPW 8      // rows per wave
#define NT 1024

typedef float v2f __attribute__((ext_vector_type(2)));

// Force 8 v2f values to be simultaneously resident in arch VGPRs here.
// Emits no instructions; only constrains the register allocator.
#define FORCE_V8(a) asm volatile("" \
    : "+v"(a[0]), "+v"(a[1]), "+v"(a[2]), "+v"(a[3]), \
      "+v"(a[4]), "+v"(a[5]), "+v"(a[6]), "+v"(a[7]))

// middle-first row order: halo-independent rows 2..6 first, then rows 0,1
// (consume hu), then row 7 (consumes hd).
__device__ constexpr int kOrd[RPW] = {2, 3, 4, 5, 6, 0, 1, 7};

// d = a * b.yx   (packed f32 mul; half-swap on src1 via op_sel, no mov needed)
__device__ __forceinline__ v2f pk_mul_yx(v2f a, v2f b) {
    v2f d;
    asm("v_pk_mul_f32 %0, %1, %2 op_sel:[0,1] op_sel_hi:[1,0]"
        : "=v"(d) : "v"(a), "v"(b));
    return d;
}
// d = a * b + c  (packed f32 fma)
__device__ __forceinline__ v2f pk_fma(v2f a, v2f b, v2f c) {
    v2f d;
    asm("v_pk_fma_f32 %0, %1, %2, %3 op_sel:[0,0,0] op_sel_hi:[1,1,1]"
        : "=v"(d) : "v"(a), "v"(b), "v"(c));
    return d;
}

__global__ void
__attribute__((amdgpu_flat_work_group_size(1024, 1024)))
__attribute__((amdgpu_waves_per_eu(4, 4)))
jacobi_flux_kernel(const float* __restrict__ k_all,
                   const int* __restrict__ iters_p,
                   float* __restrict__ out)
{
    __shared__ __align__(16) v2f sTop[2][NW][64];   // 16 KB
    __shared__ __align__(16) v2f sBot[2][NW][64];   // 16 KB

    const int b   = blockIdx.x;
    const int tid = threadIdx.x;
    const int l   = tid & 63;           // lane
    const int w   = tid >> 6;           // wave 0..15
    const int R0  = w * RPW;            // first grid row of my strip
    const int c0  = l * 2;              // first grid col of my pair
    const float* kb = k_all + b * GH * GW;
    const int iters = *iters_p;

    const int wUp = (w == 0)      ? 0      : w - 1;
    const int wDn = (w == NW - 1) ? NW - 1 : w + 1;
    const bool gTop = (w == 0);
    const bool gBot = (w == NW - 1);
    const bool lane0  = (l == 0);
    const bool lane63 = (l == 63);
    // bpermute byte-addresses for left/right lane fetch (clamped lanes get
    // a don't-care address; cndmask overwrites their result).
    const int aL = (l > 0  ? l - 1 : 0) * 4;
    const int aR = (l < 63 ? l + 1 : 0) * 4;

    // ---- one-time: normalized face conductivities, packed for the
    //      regrouped stencil: rN, rS (vertical), cM=(cE.x,cW.y), cLR=(cW.x,cE.y)
    v2f rN[RPW], rS[RPW], cM[RPW], cLR[RPW];
    #pragma unroll
    for (int i = 0; i < RPW; ++i) {
        const int r  = R0 + i;
        const int ru = (r == 0)      ? 0      : r - 1;
        const int rd = (r == GH - 1) ? GH - 1 : r + 1;
        float v[2][4];
        #pragma unroll
        for (int jj = 0; jj < 2; ++jj) {
            const int c  = c0 + jj;
            const int cl = (c == 0)      ? 0      : c - 1;
            const int cr = (c == GW - 1) ? GW - 1 : c + 1;
            float kc = kb[r * GW + c];
            float kn = 0.5f * (kc + kb[ru * GW + c]);
            float ks = 0.5f * (kc + kb[rd * GW + c]);
            float kw = 0.5f * (kc + kb[r * GW + cl]);
            float ke = 0.5f * (kc + kb[r * GW + cr]);
            float inv = 1.0f / (kn + ks + kw + ke);
            v[jj][0] = kn * inv; v[jj][1] = ks * inv;
            v[jj][2] = kw * inv; v[jj][3] = ke * inv;
        }
        rN[i]  = (v2f){v[0][0], v[1][0]};
        rS[i]  = (v2f){v[0][1], v[1][1]};
        cM[i]  = (v2f){v[0][3], v[1][2]};   // (cE.x, cW.y) pairs with cc.yx
        cLR[i] = (v2f){v[0][2], v[1][3]};   // (cW.x, cE.y) pairs with (lfv,rtv)
    }

    // ---- state ----
    v2f A[RPW], B[RPW];
    #pragma unroll
    for (int i = 0; i < RPW; ++i)
        A[i] = (R0 + i == 0) ? (v2f){1.0f, 1.0f} : (v2f){0.0f, 0.0f};

    sTop[0][w][l] = A[0];
    sBot[0][w][l] = A[RPW - 1];
    __syncthreads();

    auto step = [&](const v2f (&src)[RPW], v2f (&dst)[RPW], int rp, int wp) {
        // halo loads issued first; consumed only by rows 0,1,7 which run
        // LAST (middle-first order) so the ~120cy LDS latency is hidden.
        v2f hu = sBot[rp][wUp][l];   // grid row R0-1
        v2f hd = sTop[rp][wDn][l];   // grid row R0+RPW

        #pragma unroll
        for (int j = 0; j < RPW; ++j) {
            const int i = kOrd[j];
            v2f cc = src[i];
            // horizontal neighbors via LDS-pipe crossbar (no VALU slot):
            //   lfv = T[c0-1] = lane l-1's cc.y   (lane 0: own cc.x, clamp)
            //   rtv = T[c0+2] = lane l+1's cc.x   (lane 63: own cc.y, clamp)
            float bl = __int_as_float(
                __builtin_amdgcn_ds_bpermute(aL, __float_as_int(cc.y)));
            float br = __int_as_float(
                __builtin_amdgcn_ds_bpermute(aR, __float_as_int(cc.x)));
            v2f s;
            s.x = lane0  ? cc.x : bl;   // 1 cndmask, mask hoisted to SGPR pair
            s.y = lane63 ? cc.y : br;   // 1 cndmask
            v2f up = (i == 0)       ? hu : src[i - 1];
            v2f dn = (i == RPW - 1) ? hd : src[i + 1];
            // dst = rN*up + rS*dn + cLR*(lfv,rtv) + cM*cc.yx  (all VOP3P)
            dst[i] = pk_fma(rN[i], up,
                     pk_fma(rS[i], dn,
                     pk_fma(cLR[i], s, pk_mul_yx(cM[i], cc))));
        }
        if (gTop) dst[0]       = (v2f){1.0f, 1.0f};   // Dirichlet row 0
        if (gBot) dst[RPW - 1] = (v2f){0.0f, 0.0f};   // Dirichlet row 127

        sTop[wp][w][l] = dst[0];
        sBot[wp][w][l] = dst[RPW - 1];
        __syncthreads();
    };

    const int nPairs = iters >> 1;
    for (int it = 0; it < nPairs; ++it) {
        // Pin all 32 coef v2fs in arch VGPRs simultaneously (0 instructions).
        FORCE_V8(rN); FORCE_V8(rS); FORCE_V8(cM); FORCE_V8(cLR);
        step(A, B, 0, 1);
        step(B, A, 1, 0);
    }
    if (iters & 1) {
        step(A, B, 0, 1);
        #pragma unroll
        for (int i = 0; i < RPW; ++i) A[i] = B[i];
    }

    // ---- flux at row 64: wave 8 holds rows 64..71 (A[0]=r64, A[1]=r65) ----
    if (w == 8) {
        float partial = kb[64 * GW + c0]     * (A[1].x - A[0].x)
                      + kb[64 * GW + c0 + 1] * (A[1].y - A[0].y);
        #pragma unroll
        for (int off = 32; off > 0; off >>= 1)
            partial += __shfl_down(partial, off, 64);
        if (l == 0) out[b] = -partial;
    }
}

extern "C" void kernel_launch(void* const* d_in, const int* in_sizes, int n_in,
                              void* d_out, int out_size, void* d_ws, size_t ws_size,
                              hipStream_t stream)
{
    const float* k     = (const float*)d_in[0];
    const int*   iters = (const int*)d_in[1];
    float*       out   = (float*)d_out;
    jacobi_flux_kernel<<<dim3(8), dim3(NT), 0, stream>>>(k, iters, out);
}

// Round 14
// 577.082 us; speedup vs baseline: 1.6082x; 1.6082x over previous
//
#include <hip/hip_runtime.h>

// Batched Jacobi diffusion, B=8, 128x128, iters=1000. One 1024-thread block
// per batch. Wave-strip layout: 16 waves x 8 grid rows; lane owns a float2
// column pair. VALU-issue-bound on 8 active CUs (~85% busy there).
//
// Round 27: REVERT to r25 (best verified: 578us total / 527us dispatch).
// r26's ds_bpermute horizontal path regressed 63% (879us dispatch,
// VALUBusy 83%->39%): per-row lgkmcnt(0) drains serialized 8x ~100cy
// crossbar latencies per step; DPP's zero-latency VALU forwarding wins.
// Cross-step pipelining of the bpermutes nets ~0 (shift results live
// across the barrier -> +16 regs -> more AGPR churn; cndmasks remain).
//
// Search space now closed by measurement or arithmetic:
//  - regalloc artifacts (~60 instr/step AGPR-parking churn): 5 interventions
//    moved nothing (r14/r15/r18/r24/r25); AGPR clobber aborts (r23); coef
//    set is layout-invariant 64 floats/lane; shared-face ~80 live > 64;
//    LDS coef offload: 64KB/array doesn't fit beside 32KB halos.
//  - topology: per-step sync +2000cy (r16); fence writeback +800cy (r19);
//    IC-bypass protocol hang (r20); multi-launch 9.6us/gap (r22, 888us);
//    redundant time-blocking models >=550us at that gap.
//  - pipes: DPP minimal (2 instr/shift); bpermute measured -62% (r26).
//  - algorithmic: fixed-iteration linear recurrence; no shortcut.
// Plateau: ~85% VALU-issue on active CUs; residual ~15% = barrier/halo
// latency inherent to the 16-wave vertical dependency chain.

#define GH 128
#define GW 128
#define NW 16      // waves per block
#define RPW 8      // rows per wave
#define NT 1024

typedef float v2f __attribute__((ext_vector_type(2)));

// Force 8 v2f values to be simultaneously resident in arch VGPRs here.
// Emits no instructions; only constrains the register allocator.
#define FORCE_V8(a) asm volatile("" \
    : "+v"(a[0]), "+v"(a[1]), "+v"(a[2]), "+v"(a[3]), \
      "+v"(a[4]), "+v"(a[5]), "+v"(a[6]), "+v"(a[7]))

// middle-first row order: halo-independent rows 2..6 first, then rows 0,1
// (consume hu), then row 7 (consumes hd).
__device__ constexpr int kOrd[RPW] = {2, 3, 4, 5, 6, 0, 1, 7};

__device__ __forceinline__ float dpp_shr1(float old_v, float src) {
    // lane l gets lane l-1's src; lane 0 (invalid) keeps old_v (= left clamp)
    return __int_as_float(__builtin_amdgcn_update_dpp(
        __float_as_int(old_v), __float_as_int(src), 0x138, 0xf, 0xf, false));
}
__device__ __forceinline__ float dpp_shl1(float old_v, float src) {
    // lane l gets lane l+1's src; lane 63 (invalid) keeps old_v (= right clamp)
    return __int_as_float(__builtin_amdgcn_update_dpp(
        __float_as_int(old_v), __float_as_int(src), 0x130, 0xf, 0xf, false));
}

// d = a * b.yx   (packed f32 mul; half-swap on src1 via op_sel, no mov needed)
__device__ __forceinline__ v2f pk_mul_yx(v2f a, v2f b) {
    v2f d;
    asm("v_pk_mul_f32 %0, %1, %2 op_sel:[0,1] op_sel_hi:[1,0]"
        : "=v"(d) : "v"(a), "v"(b));
    return d;
}
// d = a * b + c  (packed f32 fma)
__device__ __forceinline__ v2f pk_fma(v2f a, v2f b, v2f c) {
    v2f d;
    asm("v_pk_fma_f32 %0, %1, %2, %3 op_sel:[0,0,0] op_sel_hi:[1,1,1]"
        : "=v"(d) : "v"(a), "v"(b), "v"(c));
    return d;
}

__global__ void
__attribute__((amdgpu_flat_work_group_size(1024, 1024)))
__attribute__((amdgpu_waves_per_eu(4, 4)))
jacobi_flux_kernel(const float* __restrict__ k_all,
                   const int* __restrict__ iters_p,
                   float* __restrict__ out)
{
    __shared__ __align__(16) v2f sTop[2][NW][64];   // 16 KB
    __shared__ __align__(16) v2f sBot[2][NW][64];   // 16 KB

    const int b   = blockIdx.x;
    const int tid = threadIdx.x;
    const int l   = tid & 63;           // lane
    const int w   = tid >> 6;           // wave 0..15
    const int R0  = w * RPW;            // first grid row of my strip
    const int c0  = l * 2;              // first grid col of my pair
    const float* kb = k_all + b * GH * GW;
    const int iters = *iters_p;

    const int wUp = (w == 0)      ? 0      : w - 1;
    const int wDn = (w == NW - 1) ? NW - 1 : w + 1;
    const bool gTop = (w == 0);
    const bool gBot = (w == NW - 1);

    // ---- one-time: normalized face conductivities, packed for the
    //      regrouped stencil: rN, rS (vertical), cM=(cE.x,cW.y), cLR=(cW.x,cE.y)
    v2f rN[RPW], rS[RPW], cM[RPW], cLR[RPW];
    #pragma unroll
    for (int i = 0; i < RPW; ++i) {
        const int r  = R0 + i;
        const int ru = (r == 0)      ? 0      : r - 1;
        const int rd = (r == GH - 1) ? GH - 1 : r + 1;
        float v[2][4];
        #pragma unroll
        for (int jj = 0; jj < 2; ++jj) {
            const int c  = c0 + jj;
            const int cl = (c == 0)      ? 0      : c - 1;
            const int cr = (c == GW - 1) ? GW - 1 : c + 1;
            float kc = kb[r * GW + c];
            float kn = 0.5f * (kc + kb[ru * GW + c]);
            float ks = 0.5f * (kc + kb[rd * GW + c]);
            float kw = 0.5f * (kc + kb[r * GW + cl]);
            float ke = 0.5f * (kc + kb[r * GW + cr]);
            float inv = 1.0f / (kn + ks + kw + ke);
            v[jj][0] = kn * inv; v[jj][1] = ks * inv;
            v[jj][2] = kw * inv; v[jj][3] = ke * inv;
        }
        rN[i]  = (v2f){v[0][0], v[1][0]};
        rS[i]  = (v2f){v[0][1], v[1][1]};
        cM[i]  = (v2f){v[0][3], v[1][2]};   // (cE.x, cW.y) pairs with cc.yx
        cLR[i] = (v2f){v[0][2], v[1][3]};   // (cW.x, cE.y) pairs with (lfv,rtv)
    }

    // ---- state ----
    v2f A[RPW], B[RPW];
    #pragma unroll
    for (int i = 0; i < RPW; ++i)
        A[i] = (R0 + i == 0) ? (v2f){1.0f, 1.0f} : (v2f){0.0f, 0.0f};

    sTop[0][w][l] = A[0];
    sBot[0][w][l] = A[RPW - 1];
    __syncthreads();

    auto step = [&](const v2f (&src)[RPW], v2f (&dst)[RPW], int rp, int wp) {
        // halo loads issued first; consumed only by rows 0,1,7 which run
        // LAST (middle-first order) so the ~120cy LDS latency is hidden.
        v2f hu = sBot[rp][wUp][l];   // grid row R0-1
        v2f hd = sTop[rp][wDn][l];   // grid row R0+RPW

        #pragma unroll
        for (int j = 0; j < RPW; ++j) {
            const int i = kOrd[j];
            v2f cc = src[i];
            // (lfv, rtv): two DPP results, used only as a packed pair
            v2f s;
            s.x = dpp_shr1(cc.x, cc.y);   // left  neighbor (clamped at col 0)
            s.y = dpp_shl1(cc.y, cc.x);   // right neighbor (clamped at col 127)
            v2f up = (i == 0)       ? hu : src[i - 1];
            v2f dn = (i == RPW - 1) ? hd : src[i + 1];
            // dst = rN*up + rS*dn + cLR*(lfv,rtv) + cM*cc.yx  (all VOP3P)
            dst[i] = pk_fma(rN[i], up,
                     pk_fma(rS[i], dn,
                     pk_fma(cLR[i], s, pk_mul_yx(cM[i], cc))));
        }
        if (gTop) dst[0]       = (v2f){1.0f, 1.0f};   // Dirichlet row 0
        if (gBot) dst[RPW - 1] = (v2f){0.0f, 0.0f};   // Dirichlet row 127

        sTop[wp][w][l] = dst[0];
        sBot[wp][w][l] = dst[RPW - 1];
        __syncthreads();
    };

    const int nPairs = iters >> 1;
    for (int it = 0; it < nPairs; ++it) {
        // Pin all 32 coef v2fs in arch VGPRs simultaneously (0 instructions).
        FORCE_V8(rN); FORCE_V8(rS); FORCE_V8(cM); FORCE_V8(cLR);
        step(A, B, 0, 1);
        step(B, A, 1, 0);
    }
    if (iters & 1) {
        step(A, B, 0, 1);
        #pragma unroll
        for (int i = 0; i < RPW; ++i) A[i] = B[i];
    }

    // ---- flux at row 64: wave 8 holds rows 64..71 (A[0]=r64, A[1]=r65) ----
    if (w == 8) {
        float partial = kb[64 * GW + c0]     * (A[1].x - A[0].x)
                      + kb[64 * GW + c0 + 1] * (A[1].y - A[0].y);
        #pragma unroll
        for (int off = 32; off > 0; off >>= 1)
            partial += __shfl_down(partial, off, 64);
        if (l == 0) out[b] = -partial;
    }
}

extern "C" void kernel_launch(void* const* d_in, const int* in_sizes, int n_in,
                              void* d_out, int out_size, void* d_ws, size_t ws_size,
                              hipStream_t stream)
{
    const float* k     = (const float*)d_in[0];
    const int*   iters = (const int*)d_in[1];
    float*       out   = (float*)d_out;
    jacobi_flux_kernel<<<dim3(8), dim3(NT), 0, stream>>>(k, iters, out);
}